// Round 2
// baseline (1457.917 us; speedup 1.0000x reference)
//
#include <hip/hip_runtime.h>
#include <hip/hip_bf16.h>
#include <math.h>

#define HH 80
#define WW 80
#define HWN 6400
#define CC 256
#define BB 16
#define MIDN 64
#define KIN 66
#define LDW 81   // padded LDS row stride

// ---------------- K0: fold BN into weights, transpose layouts ----------------
__global__ void prep_kernel(const float* __restrict__ proj_w,
                            const float* __restrict__ g1, const float* __restrict__ b1,
                            const float* __restrict__ m1, const float* __restrict__ v1,
                            const float* __restrict__ f1w,
                            const float* __restrict__ g2, const float* __restrict__ b2,
                            const float* __restrict__ m2, const float* __restrict__ v2,
                            float* __restrict__ projW_t, float* __restrict__ bias1,
                            float* __restrict__ w1t, float* __restrict__ bias2) {
    int gid = blockIdx.x * blockDim.x + threadIdx.x;
    int stride = gridDim.x * blockDim.x;
    if (gid < MIDN) {
        float s1 = g1[gid] * rsqrtf(v1[gid] + 1e-5f);
        bias1[gid] = b1[gid] - m1[gid] * s1;
        float s2 = g2[gid] * rsqrtf(v2[gid] + 1e-5f);
        bias2[gid] = b2[gid] - m2[gid] * s2;
    }
    for (int i = gid; i < CC * MIDN; i += stride) {
        int c = i / MIDN, m = i - (i / MIDN) * MIDN;
        float s1 = g1[m] * rsqrtf(v1[m] + 1e-5f);
        projW_t[i] = proj_w[m * CC + c] * s1;   // layout [c][m]
    }
    for (int i = gid; i < MIDN * KIN * 9; i += stride) {
        int t = i % 9; int km = i / 9; int m = km % MIDN; int k = km / MIDN;
        float s2 = g2[m] * rsqrtf(v2[m] + 1e-5f);
        w1t[i] = f1w[(m * KIN + k) * 9 + t] * s2;  // layout [k][m][t]
    }
}

// ---------------- K1: edge + period (per-channel heavy pass) ----------------
// grid (cg=16, b=16); each block does 16 channels of one image, accumulates
// channel-partial sums in registers, writes to partial buffers [cg*16+b][HW].
__launch_bounds__(512)
__global__ void edge_period_kernel(const float* __restrict__ x,
                                   float* __restrict__ edge_part,
                                   float* __restrict__ period_part) {
    __shared__ float Af[HH * LDW];
    __shared__ float Bf[HH * LDW];
    __shared__ float Cf[HH * LDW];
    __shared__ float Df[HH * LDW];

    int b = blockIdx.y;
    int cg = blockIdx.x;
    int tid = threadIdx.x;
    const int NR = 13;
    float er[NR], pr[NR];
#pragma unroll
    for (int r = 0; r < NR; r++) { er[r] = 0.f; pr[r] = 0.f; }

    for (int cc0 = 0; cc0 < 16; ++cc0) {
        int c = cg * 16 + cc0;
        const float* xp = x + ((size_t)(b * CC + c)) * HWN;
        __syncthreads();   // protect Af/Bf/Df from previous iteration's readers
        for (int p = tid; p < HWN; p += 512) {
            int i = p / 80, j = p - i * 80;
            Af[i * LDW + j] = xp[p];
        }
        __syncthreads();
        // --- edge (Sobel, zero pad) + resized Haar lh/hl generation ---
#pragma unroll 1
        for (int r = 0; r < NR; r++) {
            int p = tid + 512 * r;
            if (p < HWN) {
                int i = p / 80, j = p - i * 80;
                float x00 = (i > 0 && j > 0)   ? Af[(i - 1) * LDW + (j - 1)] : 0.f;
                float x01 = (i > 0)            ? Af[(i - 1) * LDW + j]       : 0.f;
                float x02 = (i > 0 && j < 79)  ? Af[(i - 1) * LDW + (j + 1)] : 0.f;
                float x10 = (j > 0)            ? Af[i * LDW + (j - 1)]       : 0.f;
                float x12 = (j < 79)           ? Af[i * LDW + (j + 1)]       : 0.f;
                float x20 = (i < 79 && j > 0)  ? Af[(i + 1) * LDW + (j - 1)] : 0.f;
                float x21 = (i < 79)           ? Af[(i + 1) * LDW + j]       : 0.f;
                float x22 = (i < 79 && j < 79) ? Af[(i + 1) * LDW + (j + 1)] : 0.f;
                float gx = (x02 - x00 + 2.f * (x12 - x10) + x22 - x20) * 0.125f;
                float gy = (x20 - x00 + 2.f * (x21 - x01) + x22 - x02) * 0.125f;
                er[r] += sqrtf(gx * gx + gy * gy);

                // bilinear resize coords (half-pixel, 79 -> 80, clamped)
                float sr = 0.9875f * (float)i - 0.00625f;
                float r0f = floorf(sr); float wr = sr - r0f;
                int ra = (int)r0f; int rb = ra + 1;
                ra = ra < 0 ? 0 : (ra > 78 ? 78 : ra);
                rb = rb < 0 ? 0 : (rb > 78 ? 78 : rb);
                float sc = 0.9875f * (float)j - 0.00625f;
                float c0f = floorf(sc); float wc = sc - c0f;
                int ca = (int)c0f; int cb = ca + 1;
                ca = ca < 0 ? 0 : (ca > 78 ? 78 : ca);
                cb = cb < 0 ? 0 : (cb > 78 ? 78 : cb);

                float lh00, hl00, lh01, hl01, lh10, hl10, lh11, hl11;
                { float s1 = Af[ra * LDW + ca], s2 = Af[ra * LDW + ca + 1],
                        s3 = Af[(ra + 1) * LDW + ca], s4 = Af[(ra + 1) * LDW + ca + 1];
                  lh00 = 0.5f * (s1 - s2 + s3 - s4); hl00 = 0.5f * (s1 + s2 - s3 - s4); }
                { float s1 = Af[ra * LDW + cb], s2 = Af[ra * LDW + cb + 1],
                        s3 = Af[(ra + 1) * LDW + cb], s4 = Af[(ra + 1) * LDW + cb + 1];
                  lh01 = 0.5f * (s1 - s2 + s3 - s4); hl01 = 0.5f * (s1 + s2 - s3 - s4); }
                { float s1 = Af[rb * LDW + ca], s2 = Af[rb * LDW + ca + 1],
                        s3 = Af[(rb + 1) * LDW + ca], s4 = Af[(rb + 1) * LDW + ca + 1];
                  lh10 = 0.5f * (s1 - s2 + s3 - s4); hl10 = 0.5f * (s1 + s2 - s3 - s4); }
                { float s1 = Af[rb * LDW + cb], s2 = Af[rb * LDW + cb + 1],
                        s3 = Af[(rb + 1) * LDW + cb], s4 = Af[(rb + 1) * LDW + cb + 1];
                  lh11 = 0.5f * (s1 - s2 + s3 - s4); hl11 = 0.5f * (s1 + s2 - s3 - s4); }

                float wru = 1.f - wr, wcu = 1.f - wc;
                float lhr = wru * (wcu * lh00 + wc * lh01) + wr * (wcu * lh10 + wc * lh11);
                float hlr = wru * (wcu * hl00 + wc * hl01) + wr * (wcu * hl10 + wc * hl11);
                Bf[i * LDW + j] = lhr;
                Cf[i * LDW + j] = hlr;
            }
        }
        __syncthreads();
        // --- P3: horizontal sums: hsum(lh) -> Af, hsum(lh^2+hl^2) -> Df ---
#pragma unroll 1
        for (int r = 0; r < NR; r++) {
            int p = tid + 512 * r;
            if (p < HWN) {
                int i = p / 80, j = p - i * 80;
                float sl = 0.f, s2s = 0.f;
#pragma unroll
                for (int dj = -2; dj <= 2; dj++) {
                    int jj = j + dj;
                    if (jj >= 0 && jj < 80) {
                        float lv = Bf[i * LDW + jj];
                        float hv = Cf[i * LDW + jj];
                        sl += lv;
                        s2s += lv * lv + hv * hv;
                    }
                }
                Af[i * LDW + j] = sl;
                Df[i * LDW + j] = s2s;
            }
        }
        __syncthreads();
        // --- P4: hsum(hl) -> Bf ---
#pragma unroll 1
        for (int r = 0; r < NR; r++) {
            int p = tid + 512 * r;
            if (p < HWN) {
                int i = p / 80, j = p - i * 80;
                float sh = 0.f;
#pragma unroll
                for (int dj = -2; dj <= 2; dj++) {
                    int jj = j + dj;
                    if (jj >= 0 && jj < 80) sh += Cf[i * LDW + jj];
                }
                Bf[i * LDW + j] = sh;
            }
        }
        __syncthreads();
        // --- P5: vertical sums + variance + accumulate period ---
#pragma unroll 1
        for (int r = 0; r < NR; r++) {
            int p = tid + 512 * r;
            if (p < HWN) {
                int i = p / 80, j = p - i * 80;
                float SL = 0.f, SH = 0.f, S2 = 0.f;
#pragma unroll
                for (int di = -2; di <= 2; di++) {
                    int ii = i + di;
                    if (ii >= 0 && ii < 80) {
                        SL += Af[ii * LDW + j];
                        SH += Bf[ii * LDW + j];
                        S2 += Df[ii * LDW + j];
                    }
                }
                float mL = SL * 0.04f, mH = SH * 0.04f, ms2 = S2 * 0.04f;
                float var = ms2 - mL * mL - mH * mH;
                var = var < 0.f ? 0.f : var;
                pr[r] += sqrtf(var + 1e-6f);
            }
        }
    }
    const float inv = 1.f / 256.f;
    float* ep = edge_part + ((size_t)(cg * BB + b)) * HWN;
    float* pp = period_part + ((size_t)(cg * BB + b)) * HWN;
#pragma unroll 1
    for (int r = 0; r < NR; r++) {
        int p = tid + 512 * r;
        if (p < HWN) {
            ep[p] = er[r] * inv;
            pp[p] = pr[r] * inv;
        }
    }
}

// ---------------- K2: reduce partials + edge density ----------------
__launch_bounds__(512)
__global__ void density_kernel(const float* __restrict__ edge_part,
                               const float* __restrict__ period_part,
                               float* __restrict__ edge_density,
                               float* __restrict__ period_sum) {
    __shared__ float E[HH * LDW];
    __shared__ float Hs[HH * LDW];
    int b = blockIdx.x;
    int tid = threadIdx.x;
    for (int p = tid; p < HWN; p += 512) {
        int i = p / 80, j = p - i * 80;
        float es = 0.f, ps = 0.f;
#pragma unroll 1
        for (int cg = 0; cg < 16; cg++) {
            es += edge_part[((size_t)(cg * BB + b)) * HWN + p];
            ps += period_part[((size_t)(cg * BB + b)) * HWN + p];
        }
        E[i * LDW + j] = es;
        period_sum[b * HWN + p] = ps;
    }
    __syncthreads();
    for (int p = tid; p < HWN; p += 512) {
        int i = p / 80, j = p - i * 80;
        float s = 0.f;
#pragma unroll
        for (int dj = -2; dj <= 2; dj++) {
            int jj = j + dj;
            if (jj >= 0 && jj < 80) s += E[i * LDW + jj];
        }
        Hs[i * LDW + j] = s;
    }
    __syncthreads();
    for (int p = tid; p < HWN; p += 512) {
        int i = p / 80, j = p - i * 80;
        float s = 0.f;
#pragma unroll
        for (int di = -2; di <= 2; di++) {
            int ii = i + di;
            if (ii >= 0 && ii < 80) s += Hs[ii * LDW + j];
        }
        edge_density[b * HWN + p] = E[i * LDW + j] / (s * 0.04f + 1e-6f);
    }
}

// ---------------- K3: projection (1x1 conv) + BN1 + SiLU ----------------
__launch_bounds__(256)
__global__ void proj_kernel(const float* __restrict__ x,
                            const float* __restrict__ Wt,
                            const float* __restrict__ bias1,
                            float* __restrict__ feat) {
    int b = blockIdx.y;
    int p = blockIdx.x * 256 + threadIdx.x;
    const float* xp = x + (size_t)b * CC * HWN + p;
    float acc[MIDN];
#pragma unroll
    for (int m = 0; m < MIDN; m++) acc[m] = bias1[m];
#pragma unroll 1
    for (int c = 0; c < CC; c += 4) {
        float x0 = xp[(size_t)(c + 0) * HWN];
        float x1 = xp[(size_t)(c + 1) * HWN];
        float x2 = xp[(size_t)(c + 2) * HWN];
        float x3 = xp[(size_t)(c + 3) * HWN];
        const float* w0 = Wt + c * MIDN;
#pragma unroll
        for (int m = 0; m < MIDN; m++) {
            float a = acc[m];
            a += x0 * w0[m];
            a += x1 * w0[MIDN + m];
            a += x2 * w0[2 * MIDN + m];
            a += x3 * w0[3 * MIDN + m];
            acc[m] = a;
        }
    }
    float* fp = feat + (size_t)b * MIDN * HWN + p;
#pragma unroll
    for (int m = 0; m < MIDN; m++) {
        float z = acc[m];
        fp[(size_t)m * HWN] = z / (1.f + expf(-z));
    }
}

// ---------------- K4: 3x3 conv + BN2 + SiLU + 1x1 + sigmoid + x*w ----------------
__launch_bounds__(256)
__global__ void fuse_kernel(const float* __restrict__ feat,
                            const float* __restrict__ edge_density,
                            const float* __restrict__ period_sum,
                            const float* __restrict__ w1t,
                            const float* __restrict__ bias2,
                            const float* __restrict__ fuse2,
                            const float* __restrict__ x,
                            float* __restrict__ out) {
    __shared__ float tile[KIN * 324];   // 66 channels x 18x18 halo tile
    int b = blockIdx.y;
    int t5 = blockIdx.x;
    int ti = t5 / 5, tj = t5 - ti * 5;
    int i0 = ti * 16, j0 = tj * 16;
    int tid = threadIdx.x;

    for (int idx = tid; idx < KIN * 324; idx += 256) {
        int ch = idx / 324;
        int rem = idx - ch * 324;
        int rr = rem / 18;
        int cc2 = rem - rr * 18;
        int gi = i0 - 1 + rr, gj = j0 - 1 + cc2;
        float v = 0.f;
        if (gi >= 0 && gi < 80 && gj >= 0 && gj < 80) {
            int p = gi * 80 + gj;
            if (ch < 64)       v = feat[((size_t)b * MIDN + ch) * HWN + p];
            else if (ch == 64) v = edge_density[b * HWN + p];
            else               v = period_sum[b * HWN + p];
        }
        tile[idx] = v;
    }
    __syncthreads();

    int li = tid / 16, lj = tid - li * 16;
    float acc[MIDN];
#pragma unroll
    for (int m = 0; m < MIDN; m++) acc[m] = bias2[m];
#pragma unroll 1
    for (int k = 0; k < KIN; k++) {
        const float* tp = tile + k * 324 + li * 18 + lj;
        float n0 = tp[0],  n1 = tp[1],  n2 = tp[2];
        float n3 = tp[18], n4 = tp[19], n5 = tp[20];
        float n6 = tp[36], n7 = tp[37], n8 = tp[38];
        const float* wk = w1t + k * MIDN * 9;
#pragma unroll
        for (int m = 0; m < MIDN; m++) {
            const float* wm = wk + m * 9;
            float a = acc[m];
            a += n0 * wm[0]; a += n1 * wm[1]; a += n2 * wm[2];
            a += n3 * wm[3]; a += n4 * wm[4]; a += n5 * wm[5];
            a += n6 * wm[6]; a += n7 * wm[7]; a += n8 * wm[8];
            acc[m] = a;
        }
    }
    float wsum = 0.f;
#pragma unroll
    for (int m = 0; m < MIDN; m++) {
        float z = acc[m];
        float y = z / (1.f + expf(-z));
        wsum += fuse2[m] * y;
    }
    float wgt = 1.f / (1.f + expf(-wsum));

    int p = (i0 + li) * 80 + (j0 + lj);
    const float* xp = x + (size_t)b * CC * HWN + p;
    float* op = out + (size_t)b * CC * HWN + p;
#pragma unroll 4
    for (int c = 0; c < CC; c++) {
        op[(size_t)c * HWN] = xp[(size_t)c * HWN] * wgt;
    }
}

// ---------------- launch ----------------
extern "C" void kernel_launch(void* const* d_in, const int* in_sizes, int n_in,
                              void* d_out, int out_size, void* d_ws, size_t ws_size,
                              hipStream_t stream) {
    (void)in_sizes; (void)n_in; (void)out_size; (void)ws_size;
    const float* x       = (const float*)d_in[0];
    const float* proj_w  = (const float*)d_in[1];
    const float* bn1_g   = (const float*)d_in[2];
    const float* bn1_b   = (const float*)d_in[3];
    const float* bn1_m   = (const float*)d_in[4];
    const float* bn1_v   = (const float*)d_in[5];
    const float* fuse1_w = (const float*)d_in[6];
    const float* bn2_g   = (const float*)d_in[7];
    const float* bn2_b   = (const float*)d_in[8];
    const float* bn2_m   = (const float*)d_in[9];
    const float* bn2_v   = (const float*)d_in[10];
    const float* fuse2_w = (const float*)d_in[11];
    float* out = (float*)d_out;

    float* ws = (float*)d_ws;
    float* edge_part    = ws;                  // 16*16*6400 = 1638400
    float* period_part  = ws + 1638400;        // 1638400
    float* edge_density = ws + 3276800;        // 102400
    float* period_sum   = ws + 3379200;        // 102400
    float* projW_t      = ws + 3481600;        // 16384
    float* bias1        = ws + 3497984;        // 64
    float* w1t          = ws + 3498048;        // 38016
    float* bias2        = ws + 3536064;        // 64
    float* feat         = ws + 3536128;        // 6553600  (total ~10.1M floats)

    prep_kernel<<<160, 256, 0, stream>>>(proj_w, bn1_g, bn1_b, bn1_m, bn1_v,
                                         fuse1_w, bn2_g, bn2_b, bn2_m, bn2_v,
                                         projW_t, bias1, w1t, bias2);
    edge_period_kernel<<<dim3(16, 16), 512, 0, stream>>>(x, edge_part, period_part);
    density_kernel<<<16, 512, 0, stream>>>(edge_part, period_part,
                                           edge_density, period_sum);
    proj_kernel<<<dim3(25, 16), 256, 0, stream>>>(x, projW_t, bias1, feat);
    fuse_kernel<<<dim3(25, 16), 256, 0, stream>>>(feat, edge_density, period_sum,
                                                  w1t, bias2, fuse2_w, x, out);
}

// Round 3
// 1253.644 us; speedup vs baseline: 1.1629x; 1.1629x over previous
//
#include <hip/hip_runtime.h>
#include <hip/hip_bf16.h>
#include <math.h>

#define HH 80
#define WW 80
#define HWN 6400
#define CC 256
#define BB 16
#define MIDN 64
#define KIN 66
#define LDW 81   // padded LDS row stride

// fuse tile geometry
#define TILE_R 4
#define TILE_C 16
#define HALO_R 6
#define HALO_C 18
#define TSZ (HALO_R * HALO_C)   // 108

// ---------------- K0: fold BN into weights, transpose layouts ----------------
__global__ void prep_kernel(const float* __restrict__ proj_w,
                            const float* __restrict__ g1, const float* __restrict__ b1,
                            const float* __restrict__ m1, const float* __restrict__ v1,
                            const float* __restrict__ f1w,
                            const float* __restrict__ g2, const float* __restrict__ b2,
                            const float* __restrict__ m2, const float* __restrict__ v2,
                            float* __restrict__ projW_t, float* __restrict__ bias1,
                            float* __restrict__ w1t, float* __restrict__ bias2) {
    int gid = blockIdx.x * blockDim.x + threadIdx.x;
    int stride = gridDim.x * blockDim.x;
    if (gid < MIDN) {
        float s1 = g1[gid] * rsqrtf(v1[gid] + 1e-5f);
        bias1[gid] = b1[gid] - m1[gid] * s1;
        float s2 = g2[gid] * rsqrtf(v2[gid] + 1e-5f);
        bias2[gid] = b2[gid] - m2[gid] * s2;
    }
    for (int i = gid; i < CC * MIDN; i += stride) {
        int c = i / MIDN, m = i - (i / MIDN) * MIDN;
        float s1 = g1[m] * rsqrtf(v1[m] + 1e-5f);
        projW_t[i] = proj_w[m * CC + c] * s1;   // layout [c][m]
    }
    for (int i = gid; i < MIDN * KIN * 9; i += stride) {
        int t = i % 9; int km = i / 9; int m = km % MIDN; int k = km / MIDN;
        float s2 = g2[m] * rsqrtf(v2[m] + 1e-5f);
        w1t[i] = f1w[(m * KIN + k) * 9 + t] * s2;  // layout [k][m][t]
    }
}

// ---------------- K1: edge + period (per-channel heavy pass) ----------------
__launch_bounds__(512)
__global__ void edge_period_kernel(const float* __restrict__ x,
                                   float* __restrict__ edge_part,
                                   float* __restrict__ period_part) {
    __shared__ float Af[HH * LDW];
    __shared__ float Bf[HH * LDW];
    __shared__ float Cf[HH * LDW];
    __shared__ float Df[HH * LDW];

    int b = blockIdx.y;
    int cg = blockIdx.x;
    int tid = threadIdx.x;
    const int NR = 13;
    float er[NR], pr[NR];
#pragma unroll
    for (int r = 0; r < NR; r++) { er[r] = 0.f; pr[r] = 0.f; }

    for (int cc0 = 0; cc0 < 16; ++cc0) {
        int c = cg * 16 + cc0;
        const float* xp = x + ((size_t)(b * CC + c)) * HWN;
        __syncthreads();
        for (int p = tid; p < HWN; p += 512) {
            int i = p / 80, j = p - i * 80;
            Af[i * LDW + j] = xp[p];
        }
        __syncthreads();
#pragma unroll 1
        for (int r = 0; r < NR; r++) {
            int p = tid + 512 * r;
            if (p < HWN) {
                int i = p / 80, j = p - i * 80;
                float x00 = (i > 0 && j > 0)   ? Af[(i - 1) * LDW + (j - 1)] : 0.f;
                float x01 = (i > 0)            ? Af[(i - 1) * LDW + j]       : 0.f;
                float x02 = (i > 0 && j < 79)  ? Af[(i - 1) * LDW + (j + 1)] : 0.f;
                float x10 = (j > 0)            ? Af[i * LDW + (j - 1)]       : 0.f;
                float x12 = (j < 79)           ? Af[i * LDW + (j + 1)]       : 0.f;
                float x20 = (i < 79 && j > 0)  ? Af[(i + 1) * LDW + (j - 1)] : 0.f;
                float x21 = (i < 79)           ? Af[(i + 1) * LDW + j]       : 0.f;
                float x22 = (i < 79 && j < 79) ? Af[(i + 1) * LDW + (j + 1)] : 0.f;
                float gx = (x02 - x00 + 2.f * (x12 - x10) + x22 - x20) * 0.125f;
                float gy = (x20 - x00 + 2.f * (x21 - x01) + x22 - x02) * 0.125f;
                er[r] += sqrtf(gx * gx + gy * gy);

                float sr = 0.9875f * (float)i - 0.00625f;
                float r0f = floorf(sr); float wr = sr - r0f;
                int ra = (int)r0f; int rb = ra + 1;
                ra = ra < 0 ? 0 : (ra > 78 ? 78 : ra);
                rb = rb < 0 ? 0 : (rb > 78 ? 78 : rb);
                float sc = 0.9875f * (float)j - 0.00625f;
                float c0f = floorf(sc); float wc = sc - c0f;
                int ca = (int)c0f; int cb = ca + 1;
                ca = ca < 0 ? 0 : (ca > 78 ? 78 : ca);
                cb = cb < 0 ? 0 : (cb > 78 ? 78 : cb);

                float lh00, hl00, lh01, hl01, lh10, hl10, lh11, hl11;
                { float s1 = Af[ra * LDW + ca], s2 = Af[ra * LDW + ca + 1],
                        s3 = Af[(ra + 1) * LDW + ca], s4 = Af[(ra + 1) * LDW + ca + 1];
                  lh00 = 0.5f * (s1 - s2 + s3 - s4); hl00 = 0.5f * (s1 + s2 - s3 - s4); }
                { float s1 = Af[ra * LDW + cb], s2 = Af[ra * LDW + cb + 1],
                        s3 = Af[(ra + 1) * LDW + cb], s4 = Af[(ra + 1) * LDW + cb + 1];
                  lh01 = 0.5f * (s1 - s2 + s3 - s4); hl01 = 0.5f * (s1 + s2 - s3 - s4); }
                { float s1 = Af[rb * LDW + ca], s2 = Af[rb * LDW + ca + 1],
                        s3 = Af[(rb + 1) * LDW + ca], s4 = Af[(rb + 1) * LDW + ca + 1];
                  lh10 = 0.5f * (s1 - s2 + s3 - s4); hl10 = 0.5f * (s1 + s2 - s3 - s4); }
                { float s1 = Af[rb * LDW + cb], s2 = Af[rb * LDW + cb + 1],
                        s3 = Af[(rb + 1) * LDW + cb], s4 = Af[(rb + 1) * LDW + cb + 1];
                  lh11 = 0.5f * (s1 - s2 + s3 - s4); hl11 = 0.5f * (s1 + s2 - s3 - s4); }

                float wru = 1.f - wr, wcu = 1.f - wc;
                float lhr = wru * (wcu * lh00 + wc * lh01) + wr * (wcu * lh10 + wc * lh11);
                float hlr = wru * (wcu * hl00 + wc * hl01) + wr * (wcu * hl10 + wc * hl11);
                Bf[i * LDW + j] = lhr;
                Cf[i * LDW + j] = hlr;
            }
        }
        __syncthreads();
#pragma unroll 1
        for (int r = 0; r < NR; r++) {
            int p = tid + 512 * r;
            if (p < HWN) {
                int i = p / 80, j = p - i * 80;
                float sl = 0.f, s2s = 0.f;
#pragma unroll
                for (int dj = -2; dj <= 2; dj++) {
                    int jj = j + dj;
                    if (jj >= 0 && jj < 80) {
                        float lv = Bf[i * LDW + jj];
                        float hv = Cf[i * LDW + jj];
                        sl += lv;
                        s2s += lv * lv + hv * hv;
                    }
                }
                Af[i * LDW + j] = sl;
                Df[i * LDW + j] = s2s;
            }
        }
        __syncthreads();
#pragma unroll 1
        for (int r = 0; r < NR; r++) {
            int p = tid + 512 * r;
            if (p < HWN) {
                int i = p / 80, j = p - i * 80;
                float sh = 0.f;
#pragma unroll
                for (int dj = -2; dj <= 2; dj++) {
                    int jj = j + dj;
                    if (jj >= 0 && jj < 80) sh += Cf[i * LDW + jj];
                }
                Bf[i * LDW + j] = sh;
            }
        }
        __syncthreads();
#pragma unroll 1
        for (int r = 0; r < NR; r++) {
            int p = tid + 512 * r;
            if (p < HWN) {
                int i = p / 80, j = p - i * 80;
                float SL = 0.f, SH = 0.f, S2 = 0.f;
#pragma unroll
                for (int di = -2; di <= 2; di++) {
                    int ii = i + di;
                    if (ii >= 0 && ii < 80) {
                        SL += Af[ii * LDW + j];
                        SH += Bf[ii * LDW + j];
                        S2 += Df[ii * LDW + j];
                    }
                }
                float mL = SL * 0.04f, mH = SH * 0.04f, ms2 = S2 * 0.04f;
                float var = ms2 - mL * mL - mH * mH;
                var = var < 0.f ? 0.f : var;
                pr[r] += sqrtf(var + 1e-6f);
            }
        }
    }
    const float inv = 1.f / 256.f;
    float* ep = edge_part + ((size_t)(cg * BB + b)) * HWN;
    float* pp = period_part + ((size_t)(cg * BB + b)) * HWN;
#pragma unroll 1
    for (int r = 0; r < NR; r++) {
        int p = tid + 512 * r;
        if (p < HWN) {
            ep[p] = er[r] * inv;
            pp[p] = pr[r] * inv;
        }
    }
}

// ---------------- K2: reduce partials + edge density ----------------
__launch_bounds__(512)
__global__ void density_kernel(const float* __restrict__ edge_part,
                               const float* __restrict__ period_part,
                               float* __restrict__ edge_density,
                               float* __restrict__ period_sum) {
    __shared__ float E[HH * LDW];
    __shared__ float Hs[HH * LDW];
    int b = blockIdx.x;
    int tid = threadIdx.x;
    for (int p = tid; p < HWN; p += 512) {
        int i = p / 80, j = p - i * 80;
        float es = 0.f, ps = 0.f;
#pragma unroll 1
        for (int cg = 0; cg < 16; cg++) {
            es += edge_part[((size_t)(cg * BB + b)) * HWN + p];
            ps += period_part[((size_t)(cg * BB + b)) * HWN + p];
        }
        E[i * LDW + j] = es;
        period_sum[b * HWN + p] = ps;
    }
    __syncthreads();
    for (int p = tid; p < HWN; p += 512) {
        int i = p / 80, j = p - i * 80;
        float s = 0.f;
#pragma unroll
        for (int dj = -2; dj <= 2; dj++) {
            int jj = j + dj;
            if (jj >= 0 && jj < 80) s += E[i * LDW + jj];
        }
        Hs[i * LDW + j] = s;
    }
    __syncthreads();
    for (int p = tid; p < HWN; p += 512) {
        int i = p / 80, j = p - i * 80;
        float s = 0.f;
#pragma unroll
        for (int di = -2; di <= 2; di++) {
            int ii = i + di;
            if (ii >= 0 && ii < 80) s += Hs[ii * LDW + j];
        }
        edge_density[b * HWN + p] = E[i * LDW + j] / (s * 0.04f + 1e-6f);
    }
}

// ---------------- K3: projection (1x1 conv) + BN1 + SiLU, m-split ----------------
// grid (100, 16); block 256 = 4 waves; wave w -> m in [16w,16w+16), lane -> pixel.
__launch_bounds__(256)
__global__ void proj_kernel(const float* __restrict__ x,
                            const float* __restrict__ Wt,
                            const float* __restrict__ bias1,
                            float* __restrict__ feat) {
    __shared__ float xs[64 * 64];   // 16 KB: [c-chunk 64][px 64]
    int b = blockIdx.y;
    int p0 = blockIdx.x * 64;
    int tid = threadIdx.x;
    int w = tid >> 6, lane = tid & 63;

    float acc[16];
    const float* bp = bias1 + w * 16;
#pragma unroll
    for (int m = 0; m < 16; m++) acc[m] = bp[m];

#pragma unroll 1
    for (int c0 = 0; c0 < CC; c0 += 64) {
        __syncthreads();
#pragma unroll
        for (int r = 0; r < 16; r++) {
            int idx = tid + r * 256;          // idx = cc*64 + l
            int cc = idx >> 6, l = idx & 63;
            xs[idx] = x[((size_t)(b * CC + c0 + cc)) * HWN + p0 + l];
        }
        __syncthreads();
#pragma unroll 4
        for (int cc = 0; cc < 64; cc++) {
            float xv = xs[cc * 64 + lane];
            const float* wp = Wt + (c0 + cc) * MIDN + w * 16;
#pragma unroll
            for (int m = 0; m < 16; m++) acc[m] += xv * wp[m];
        }
    }
    float* fp = feat + (size_t)b * MIDN * HWN + p0 + lane;
#pragma unroll
    for (int m = 0; m < 16; m++) {
        float z = acc[m];
        fp[(size_t)(w * 16 + m) * HWN] = z / (1.f + expf(-z));
    }
}

// ---------------- K4: 3x3 conv + BN2 + SiLU + 1x1 + sigmoid + x*w, m-split ----------------
// grid (100, 16); tile 4x16 px; block 256 = 4 waves; wave w -> m in [16w,16w+16).
__launch_bounds__(256)
__global__ void fuse_kernel(const float* __restrict__ feat,
                            const float* __restrict__ edge_density,
                            const float* __restrict__ period_sum,
                            const float* __restrict__ w1t,
                            const float* __restrict__ bias2,
                            const float* __restrict__ fuse2,
                            const float* __restrict__ x,
                            float* __restrict__ out) {
    __shared__ float tile[KIN * TSZ];   // 66*108*4 = 28512 B
    __shared__ float part[4][64];
    int b = blockIdx.y;
    int t = blockIdx.x;                 // 0..99
    int ti = t / 5, tj = t - ti * 5;    // 20 row-tiles x 5 col-tiles
    int i0 = ti * TILE_R, j0 = tj * TILE_C;
    int tid = threadIdx.x;
    int w = tid >> 6, lane = tid & 63;

    for (int idx = tid; idx < KIN * TSZ; idx += 256) {
        int ch = idx / TSZ;
        int rem = idx - ch * TSZ;
        int rr = rem / HALO_C, cc2 = rem - rr * HALO_C;
        int gi = i0 - 1 + rr, gj = j0 - 1 + cc2;
        float v = 0.f;
        if (gi >= 0 && gi < 80 && gj >= 0 && gj < 80) {
            int p = gi * 80 + gj;
            if (ch < 64)       v = feat[((size_t)b * MIDN + ch) * HWN + p];
            else if (ch == 64) v = edge_density[b * HWN + p];
            else               v = period_sum[b * HWN + p];
        }
        tile[idx] = v;
    }
    __syncthreads();

    int li = lane >> 4, lj = lane & 15;   // 4 rows x 16 cols
    float acc[16];
    const float* bp = bias2 + w * 16;
#pragma unroll
    for (int m = 0; m < 16; m++) acc[m] = bp[m];

#pragma unroll 2
    for (int k = 0; k < KIN; k++) {
        const float* tp = tile + k * TSZ + li * HALO_C + lj;
        float n0 = tp[0],  n1 = tp[1],  n2 = tp[2];
        float n3 = tp[HALO_C],     n4 = tp[HALO_C + 1],     n5 = tp[HALO_C + 2];
        float n6 = tp[2 * HALO_C], n7 = tp[2 * HALO_C + 1], n8 = tp[2 * HALO_C + 2];
        const float* wk = w1t + (size_t)(k * MIDN + w * 16) * 9;
#pragma unroll
        for (int m = 0; m < 16; m++) {
            const float* wm = wk + m * 9;
            float a = acc[m];
            a += n0 * wm[0]; a += n1 * wm[1]; a += n2 * wm[2];
            a += n3 * wm[3]; a += n4 * wm[4]; a += n5 * wm[5];
            a += n6 * wm[6]; a += n7 * wm[7]; a += n8 * wm[8];
            acc[m] = a;
        }
    }
    float wsum = 0.f;
    const float* f2 = fuse2 + w * 16;
#pragma unroll
    for (int m = 0; m < 16; m++) {
        float z = acc[m];
        wsum += f2[m] * (z / (1.f + expf(-z)));
    }
    part[w][lane] = wsum;
    __syncthreads();
    float tot = part[0][lane] + part[1][lane] + part[2][lane] + part[3][lane];
    float wgt = 1.f / (1.f + expf(-tot));

    int gi = i0 + li, gj = j0 + lj;
    size_t base = (size_t)b * CC * HWN + (size_t)(gi * 80 + gj);
    const float* xp = x + base;
    float* op = out + base;
#pragma unroll 4
    for (int c = w * 64; c < w * 64 + 64; c++) {
        op[(size_t)c * HWN] = xp[(size_t)c * HWN] * wgt;
    }
}

// ---------------- launch ----------------
extern "C" void kernel_launch(void* const* d_in, const int* in_sizes, int n_in,
                              void* d_out, int out_size, void* d_ws, size_t ws_size,
                              hipStream_t stream) {
    (void)in_sizes; (void)n_in; (void)out_size; (void)ws_size;
    const float* x       = (const float*)d_in[0];
    const float* proj_w  = (const float*)d_in[1];
    const float* bn1_g   = (const float*)d_in[2];
    const float* bn1_b   = (const float*)d_in[3];
    const float* bn1_m   = (const float*)d_in[4];
    const float* bn1_v   = (const float*)d_in[5];
    const float* fuse1_w = (const float*)d_in[6];
    const float* bn2_g   = (const float*)d_in[7];
    const float* bn2_b   = (const float*)d_in[8];
    const float* bn2_m   = (const float*)d_in[9];
    const float* bn2_v   = (const float*)d_in[10];
    const float* fuse2_w = (const float*)d_in[11];
    float* out = (float*)d_out;

    float* ws = (float*)d_ws;
    float* edge_part    = ws;                  // 16*16*6400 = 1638400
    float* period_part  = ws + 1638400;        // 1638400
    float* edge_density = ws + 3276800;        // 102400
    float* period_sum   = ws + 3379200;        // 102400
    float* projW_t      = ws + 3481600;        // 16384
    float* bias1        = ws + 3497984;        // 64
    float* w1t          = ws + 3498048;        // 38016
    float* bias2        = ws + 3536064;        // 64
    float* feat         = ws + 3536128;        // 6553600

    prep_kernel<<<160, 256, 0, stream>>>(proj_w, bn1_g, bn1_b, bn1_m, bn1_v,
                                         fuse1_w, bn2_g, bn2_b, bn2_m, bn2_v,
                                         projW_t, bias1, w1t, bias2);
    edge_period_kernel<<<dim3(16, 16), 512, 0, stream>>>(x, edge_part, period_part);
    density_kernel<<<16, 512, 0, stream>>>(edge_part, period_part,
                                           edge_density, period_sum);
    proj_kernel<<<dim3(100, 16), 256, 0, stream>>>(x, projW_t, bias1, feat);
    fuse_kernel<<<dim3(100, 16), 256, 0, stream>>>(feat, edge_density, period_sum,
                                                   w1t, bias2, fuse2_w, x, out);
}

// Round 5
// 556.248 us; speedup vs baseline: 2.6210x; 2.2537x over previous
//
#include <hip/hip_runtime.h>
#include <hip/hip_bf16.h>
#include <math.h>

#define HH 80
#define WW 80
#define HWN 6400
#define CC 256
#define BB 16
#define MIDN 64
#define LDW 81   // padded LDS row stride (edge kernels)

typedef _Float16 f16x8 __attribute__((ext_vector_type(8)));
typedef _Float16 f16x4 __attribute__((ext_vector_type(4)));
typedef float    f32x4 __attribute__((ext_vector_type(4)));
typedef int      i32x4 __attribute__((ext_vector_type(4)));

// ---------------- K0: fold BN, pack MFMA A-fragments (fp16) ----------------
// A-frag lane map for mfma_f32_16x16x32_f16: row m = lane&15, k = 8*(lane>>4)+j
__global__ void prep_kernel(const float* __restrict__ proj_w,
                            const float* __restrict__ g1, const float* __restrict__ b1,
                            const float* __restrict__ m1, const float* __restrict__ v1,
                            const float* __restrict__ f1w,
                            const float* __restrict__ g2, const float* __restrict__ b2,
                            const float* __restrict__ m2, const float* __restrict__ v2,
                            _Float16* __restrict__ apack_proj,   // [c8][w4][lane64][j8]
                            _Float16* __restrict__ apack_fuse,   // [t9][c3][w4][lane64][j8]
                            float* __restrict__ bias1, float* __restrict__ bias2) {
    int gid = blockIdx.x * blockDim.x + threadIdx.x;
    int stride = gridDim.x * blockDim.x;
    if (gid < MIDN) {
        float s1 = g1[gid] * rsqrtf(v1[gid] + 1e-5f);
        bias1[gid] = b1[gid] - m1[gid] * s1;
        float s2 = g2[gid] * rsqrtf(v2[gid] + 1e-5f);
        bias2[gid] = b2[gid] - m2[gid] * s2;
    }
    for (int i = gid; i < 8 * 4 * 64 * 8; i += stride) {
        int j = i & 7, lane = (i >> 3) & 63, w = (i >> 9) & 3, c = i >> 11;
        int m = w * 16 + (lane & 15);
        int ch = c * 32 + (lane >> 4) * 8 + j;
        float s1 = g1[m] * rsqrtf(v1[m] + 1e-5f);
        apack_proj[i] = (_Float16)(proj_w[m * CC + ch] * s1);
    }
    for (int i = gid; i < 9 * 3 * 4 * 64 * 8; i += stride) {
        int j = i & 7, lane = (i >> 3) & 63, w = (i >> 9) & 3;
        int tc = i >> 11; int c = tc % 3, t = tc / 3;
        int m = w * 16 + (lane & 15);
        int ch = c * 32 + (lane >> 4) * 8 + j;
        float s2 = g2[m] * rsqrtf(v2[m] + 1e-5f);
        float v = 0.f;
        if (ch < 66) v = f1w[(m * 66 + ch) * 9 + t] * s2;
        apack_fuse[i] = (_Float16)v;
    }
}

// ---------------- K1: edge + period (unchanged) ----------------
__launch_bounds__(512)
__global__ void edge_period_kernel(const float* __restrict__ x,
                                   float* __restrict__ edge_part,
                                   float* __restrict__ period_part) {
    __shared__ float Af[HH * LDW];
    __shared__ float Bf[HH * LDW];
    __shared__ float Cf[HH * LDW];
    __shared__ float Df[HH * LDW];

    int b = blockIdx.y;
    int cg = blockIdx.x;
    int tid = threadIdx.x;
    const int NR = 13;
    float er[NR], pr[NR];
#pragma unroll
    for (int r = 0; r < NR; r++) { er[r] = 0.f; pr[r] = 0.f; }

    for (int cc0 = 0; cc0 < 16; ++cc0) {
        int c = cg * 16 + cc0;
        const float* xp = x + ((size_t)(b * CC + c)) * HWN;
        __syncthreads();
        for (int p = tid; p < HWN; p += 512) {
            int i = p / 80, j = p - i * 80;
            Af[i * LDW + j] = xp[p];
        }
        __syncthreads();
#pragma unroll 1
        for (int r = 0; r < NR; r++) {
            int p = tid + 512 * r;
            if (p < HWN) {
                int i = p / 80, j = p - i * 80;
                float x00 = (i > 0 && j > 0)   ? Af[(i - 1) * LDW + (j - 1)] : 0.f;
                float x01 = (i > 0)            ? Af[(i - 1) * LDW + j]       : 0.f;
                float x02 = (i > 0 && j < 79)  ? Af[(i - 1) * LDW + (j + 1)] : 0.f;
                float x10 = (j > 0)            ? Af[i * LDW + (j - 1)]       : 0.f;
                float x12 = (j < 79)           ? Af[i * LDW + (j + 1)]       : 0.f;
                float x20 = (i < 79 && j > 0)  ? Af[(i + 1) * LDW + (j - 1)] : 0.f;
                float x21 = (i < 79)           ? Af[(i + 1) * LDW + j]       : 0.f;
                float x22 = (i < 79 && j < 79) ? Af[(i + 1) * LDW + (j + 1)] : 0.f;
                float gx = (x02 - x00 + 2.f * (x12 - x10) + x22 - x20) * 0.125f;
                float gy = (x20 - x00 + 2.f * (x21 - x01) + x22 - x02) * 0.125f;
                er[r] += sqrtf(gx * gx + gy * gy);

                float sr = 0.9875f * (float)i - 0.00625f;
                float r0f = floorf(sr); float wr = sr - r0f;
                int ra = (int)r0f; int rb = ra + 1;
                ra = ra < 0 ? 0 : (ra > 78 ? 78 : ra);
                rb = rb < 0 ? 0 : (rb > 78 ? 78 : rb);
                float sc = 0.9875f * (float)j - 0.00625f;
                float c0f = floorf(sc); float wc = sc - c0f;
                int ca = (int)c0f; int cb = ca + 1;
                ca = ca < 0 ? 0 : (ca > 78 ? 78 : ca);
                cb = cb < 0 ? 0 : (cb > 78 ? 78 : cb);

                float lh00, hl00, lh01, hl01, lh10, hl10, lh11, hl11;
                { float s1 = Af[ra * LDW + ca], s2 = Af[ra * LDW + ca + 1],
                        s3 = Af[(ra + 1) * LDW + ca], s4 = Af[(ra + 1) * LDW + ca + 1];
                  lh00 = 0.5f * (s1 - s2 + s3 - s4); hl00 = 0.5f * (s1 + s2 - s3 - s4); }
                { float s1 = Af[ra * LDW + cb], s2 = Af[ra * LDW + cb + 1],
                        s3 = Af[(ra + 1) * LDW + cb], s4 = Af[(ra + 1) * LDW + cb + 1];
                  lh01 = 0.5f * (s1 - s2 + s3 - s4); hl01 = 0.5f * (s1 + s2 - s3 - s4); }
                { float s1 = Af[rb * LDW + ca], s2 = Af[rb * LDW + ca + 1],
                        s3 = Af[(rb + 1) * LDW + ca], s4 = Af[(rb + 1) * LDW + ca + 1];
                  lh10 = 0.5f * (s1 - s2 + s3 - s4); hl10 = 0.5f * (s1 + s2 - s3 - s4); }
                { float s1 = Af[rb * LDW + cb], s2 = Af[rb * LDW + cb + 1],
                        s3 = Af[(rb + 1) * LDW + cb], s4 = Af[(rb + 1) * LDW + cb + 1];
                  lh11 = 0.5f * (s1 - s2 + s3 - s4); hl11 = 0.5f * (s1 + s2 - s3 - s4); }

                float wru = 1.f - wr, wcu = 1.f - wc;
                float lhr = wru * (wcu * lh00 + wc * lh01) + wr * (wcu * lh10 + wc * lh11);
                float hlr = wru * (wcu * hl00 + wc * hl01) + wr * (wcu * hl10 + wc * hl11);
                Bf[i * LDW + j] = lhr;
                Cf[i * LDW + j] = hlr;
            }
        }
        __syncthreads();
#pragma unroll 1
        for (int r = 0; r < NR; r++) {
            int p = tid + 512 * r;
            if (p < HWN) {
                int i = p / 80, j = p - i * 80;
                float sl = 0.f, s2s = 0.f;
#pragma unroll
                for (int dj = -2; dj <= 2; dj++) {
                    int jj = j + dj;
                    if (jj >= 0 && jj < 80) {
                        float lv = Bf[i * LDW + jj];
                        float hv = Cf[i * LDW + jj];
                        sl += lv;
                        s2s += lv * lv + hv * hv;
                    }
                }
                Af[i * LDW + j] = sl;
                Df[i * LDW + j] = s2s;
            }
        }
        __syncthreads();
#pragma unroll 1
        for (int r = 0; r < NR; r++) {
            int p = tid + 512 * r;
            if (p < HWN) {
                int i = p / 80, j = p - i * 80;
                float sh = 0.f;
#pragma unroll
                for (int dj = -2; dj <= 2; dj++) {
                    int jj = j + dj;
                    if (jj >= 0 && jj < 80) sh += Cf[i * LDW + jj];
                }
                Bf[i * LDW + j] = sh;
            }
        }
        __syncthreads();
#pragma unroll 1
        for (int r = 0; r < NR; r++) {
            int p = tid + 512 * r;
            if (p < HWN) {
                int i = p / 80, j = p - i * 80;
                float SL = 0.f, SH = 0.f, S2 = 0.f;
#pragma unroll
                for (int di = -2; di <= 2; di++) {
                    int ii = i + di;
                    if (ii >= 0 && ii < 80) {
                        SL += Af[ii * LDW + j];
                        SH += Bf[ii * LDW + j];
                        S2 += Df[ii * LDW + j];
                    }
                }
                float mL = SL * 0.04f, mH = SH * 0.04f, ms2 = S2 * 0.04f;
                float var = ms2 - mL * mL - mH * mH;
                var = var < 0.f ? 0.f : var;
                pr[r] += sqrtf(var + 1e-6f);
            }
        }
    }
    const float inv = 1.f / 256.f;
    float* ep = edge_part + ((size_t)(cg * BB + b)) * HWN;
    float* pp = period_part + ((size_t)(cg * BB + b)) * HWN;
#pragma unroll 1
    for (int r = 0; r < NR; r++) {
        int p = tid + 512 * r;
        if (p < HWN) {
            ep[p] = er[r] * inv;
            pp[p] = pr[r] * inv;
        }
    }
}

// ---------------- K2: reduce partials + edge density -> feat_t ch 64..95 ----------------
__launch_bounds__(512)
__global__ void density_kernel(const float* __restrict__ edge_part,
                               const float* __restrict__ period_part,
                               _Float16* __restrict__ feat_t) {
    __shared__ float E[HH * LDW];
    __shared__ float Hs[HH * LDW];
    __shared__ float Ps[HH * LDW];
    int b = blockIdx.x;
    int tid = threadIdx.x;
    for (int p = tid; p < HWN; p += 512) {
        int i = p / 80, j = p - i * 80;
        float es = 0.f, ps = 0.f;
#pragma unroll 1
        for (int cg = 0; cg < 16; cg++) {
            es += edge_part[((size_t)(cg * BB + b)) * HWN + p];
            ps += period_part[((size_t)(cg * BB + b)) * HWN + p];
        }
        E[i * LDW + j] = es;
        Ps[i * LDW + j] = ps;
    }
    __syncthreads();
    for (int p = tid; p < HWN; p += 512) {
        int i = p / 80, j = p - i * 80;
        float s = 0.f;
#pragma unroll
        for (int dj = -2; dj <= 2; dj++) {
            int jj = j + dj;
            if (jj >= 0 && jj < 80) s += E[i * LDW + jj];
        }
        Hs[i * LDW + j] = s;
    }
    __syncthreads();
    for (int p = tid; p < HWN; p += 512) {
        int i = p / 80, j = p - i * 80;
        float s = 0.f;
#pragma unroll
        for (int di = -2; di <= 2; di++) {
            int ii = i + di;
            if (ii >= 0 && ii < 80) s += Hs[ii * LDW + j];
        }
        float ed = E[i * LDW + j] / (s * 0.04f + 1e-6f);
        float pd = Ps[i * LDW + j];
        _Float16* fp = feat_t + ((size_t)(b * HWN + p)) * 96;
        f16x8 z8 = {};
        f16x8 f8 = {};
        f8[0] = (_Float16)ed; f8[1] = (_Float16)pd;
        *reinterpret_cast<f16x8*>(fp + 64) = f8;
        *reinterpret_cast<f16x8*>(fp + 72) = z8;
        *reinterpret_cast<f16x8*>(fp + 80) = z8;
        *reinterpret_cast<f16x8*>(fp + 88) = z8;
    }
}

// ---------------- K3: proj via MFMA: feat_t[b][px][0..63] = silu(BN(Wx)) ----------------
// block 256 = 4 waves (m-slice 16w); px tile = 64; K = 256 (8 chunks of 32)
__launch_bounds__(256)
__global__ void proj_kernel(const float* __restrict__ x,
                            const _Float16* __restrict__ apack,
                            const float* __restrict__ bias1,
                            _Float16* __restrict__ feat_t) {
    __shared__ __align__(16) unsigned char lds[64 * 512];   // Xt[px][ch] f16, swizzled
    int b = blockIdx.y, p0 = blockIdx.x * 64;
    int tid = threadIdx.x, w = tid >> 6, l = tid & 63;

    // stage x tile -> LDS transposed f16 (wave w covers ch0 = i*16 + w*4 .. +3)
#pragma unroll 4
    for (int i = 0; i < 16; i++) {
        int ch0 = i * 16 + w * 4;
        f16x4 v4;
#pragma unroll
        for (int q = 0; q < 4; q++)
            v4[q] = (_Float16)x[((size_t)(b * CC + ch0 + q)) * HWN + p0 + l];
        int byte = l * 512 + ((ch0 * 2) ^ ((l & 7) << 4));
        *reinterpret_cast<f16x4*>(lds + byte) = v4;
    }
    __syncthreads();

    const f16x8* Ap = reinterpret_cast<const f16x8*>(apack);
    f32x4 acc[4];
#pragma unroll
    for (int ct = 0; ct < 4; ct++) acc[ct] = (f32x4){0.f, 0.f, 0.f, 0.f};

    int kb = 16 * (l >> 4);
#pragma unroll 2
    for (int c = 0; c < 8; c++) {
        f16x8 a = Ap[(c * 4 + w) * 64 + l];
#pragma unroll
        for (int ct = 0; ct < 4; ct++) {
            int byte = (ct * 16 + (l & 15)) * 512 + ((c * 64 + kb) ^ ((l & 7) << 4));
            f16x8 bv = *reinterpret_cast<const f16x8*>(lds + byte);
            acc[ct] = __builtin_amdgcn_mfma_f32_16x16x32_f16(a, bv, acc[ct], 0, 0, 0);
        }
    }

    float b1v[4];
#pragma unroll
    for (int q = 0; q < 4; q++) b1v[q] = bias1[w * 16 + (l >> 4) * 4 + q];
#pragma unroll
    for (int ct = 0; ct < 4; ct++) {
        f16x4 o4;
#pragma unroll
        for (int q = 0; q < 4; q++) {
            float z = acc[ct][q] + b1v[q];
            o4[q] = (_Float16)(z / (1.f + expf(-z)));
        }
        size_t px = (size_t)(b * HWN) + p0 + ct * 16 + (l & 15);
        *reinterpret_cast<f16x4*>(feat_t + px * 96 + w * 16 + (l >> 4) * 4) = o4;
    }
}

// ---------------- K4: fuse via MFMA + epilogue + x*wgt ----------------
// block 256 = 4 waves (m-slice); px tile 4x16; halo tile rows padded to 256 B
#define TROW 256
__launch_bounds__(256)
__global__ void fuse_kernel(const _Float16* __restrict__ feat_t,
                            const _Float16* __restrict__ apack,
                            const float* __restrict__ bias2,
                            const float* __restrict__ fuse2,
                            const float* __restrict__ x,
                            float* __restrict__ out) {
    __shared__ __align__(16) unsigned char tl[108 * TROW];  // [hpx 6x18][ch 96 f16], 256B rows
    __shared__ float R[4 * 4 * 4 * 16];
    __shared__ float wgtbuf[64];
    int b = blockIdx.y, t5 = blockIdx.x;
    int ti = t5 / 5, tj = t5 - ti * 5;
    int i0 = ti * 4, j0 = tj * 16;
    int tid = threadIdx.x, w = tid >> 6, l = tid & 63;

    // stage halo tile: 108 hpx x 12 granules of 16B
    for (int idx = tid; idx < 1296; idx += 256) {
        int hpx = idx / 12, g = idx - hpx * 12;
        int hr = hpx / 18, hc = hpx - hr * 18;
        int gi = i0 - 1 + hr, gj = j0 - 1 + hc;
        i32x4 val = {0, 0, 0, 0};
        if (gi >= 0 && gi < 80 && gj >= 0 && gj < 80) {
            val = *reinterpret_cast<const i32x4*>(
                feat_t + ((size_t)(b * HWN) + gi * 80 + gj) * 96 + g * 8);
        }
        *reinterpret_cast<i32x4*>(tl + hpx * TROW + ((g * 16) ^ ((hc & 7) << 4))) = val;
    }
    __syncthreads();

    const f16x8* Ap = reinterpret_cast<const f16x8*>(apack);
    f32x4 acc[4];
#pragma unroll
    for (int r = 0; r < 4; r++) acc[r] = (f32x4){0.f, 0.f, 0.f, 0.f};
    int kb = 16 * (l >> 4);

#pragma unroll 1
    for (int t = 0; t < 9; t++) {
        int dy = t / 3, dx = t - dy * 3;
        f16x8 a0 = Ap[((t * 3 + 0) * 4 + w) * 64 + l];
        f16x8 a1 = Ap[((t * 3 + 1) * 4 + w) * 64 + l];
        f16x8 a2 = Ap[((t * 3 + 2) * 4 + w) * 64 + l];
        int hc = (l & 15) + dx;
        int key = (hc & 7) << 4;
#pragma unroll
        for (int r = 0; r < 4; r++) {
            int base = ((r + dy) * 18 + hc) * TROW;
            f16x8 b0 = *reinterpret_cast<const f16x8*>(tl + base + ((0 + kb) ^ key));
            acc[r] = __builtin_amdgcn_mfma_f32_16x16x32_f16(a0, b0, acc[r], 0, 0, 0);
            f16x8 b1_ = *reinterpret_cast<const f16x8*>(tl + base + ((64 + kb) ^ key));
            acc[r] = __builtin_amdgcn_mfma_f32_16x16x32_f16(a1, b1_, acc[r], 0, 0, 0);
            f16x8 b2_ = *reinterpret_cast<const f16x8*>(tl + base + ((128 + kb) ^ key));
            acc[r] = __builtin_amdgcn_mfma_f32_16x16x32_f16(a2, b2_, acc[r], 0, 0, 0);
        }
    }

    float b2v[4], f2v[4];
#pragma unroll
    for (int q = 0; q < 4; q++) {
        int m = w * 16 + (l >> 4) * 4 + q;
        b2v[q] = bias2[m];
        f2v[q] = fuse2[m];
    }
#pragma unroll
    for (int r = 0; r < 4; r++) {
        float p = 0.f;
#pragma unroll
        for (int q = 0; q < 4; q++) {
            float z = acc[r][q] + b2v[q];
            p += f2v[q] * (z / (1.f + expf(-z)));
        }
        R[((w * 4 + r) * 4 + (l >> 4)) * 16 + (l & 15)] = p;
    }
    __syncthreads();
    if (tid < 64) {
        int r = tid >> 4, cc = tid & 15;
        float s = 0.f;
#pragma unroll
        for (int w2 = 0; w2 < 4; w2++)
#pragma unroll
            for (int g2 = 0; g2 < 4; g2++)
                s += R[((w2 * 4 + r) * 4 + g2) * 16 + cc];
        wgtbuf[tid] = 1.f / (1.f + expf(-s));
    }
    __syncthreads();

    int r = l >> 4, cc = l & 15;
    float wgt = wgtbuf[l];
    size_t base = (size_t)b * CC * HWN + (size_t)((i0 + r) * 80 + j0 + cc);
    const float* xp = x + base;
    float* op = out + base;
#pragma unroll 4
    for (int ch = w * 64; ch < w * 64 + 64; ch++) {
        op[(size_t)ch * HWN] = xp[(size_t)ch * HWN] * wgt;
    }
}

// ---------------- launch ----------------
extern "C" void kernel_launch(void* const* d_in, const int* in_sizes, int n_in,
                              void* d_out, int out_size, void* d_ws, size_t ws_size,
                              hipStream_t stream) {
    (void)in_sizes; (void)n_in; (void)out_size; (void)ws_size;
    const float* x       = (const float*)d_in[0];
    const float* proj_w  = (const float*)d_in[1];
    const float* bn1_g   = (const float*)d_in[2];
    const float* bn1_b   = (const float*)d_in[3];
    const float* bn1_m   = (const float*)d_in[4];
    const float* bn1_v   = (const float*)d_in[5];
    const float* fuse1_w = (const float*)d_in[6];
    const float* bn2_g   = (const float*)d_in[7];
    const float* bn2_b   = (const float*)d_in[8];
    const float* bn2_m   = (const float*)d_in[9];
    const float* bn2_v   = (const float*)d_in[10];
    const float* fuse2_w = (const float*)d_in[11];
    float* out = (float*)d_out;

    float* ws = (float*)d_ws;
    float*    edge_part   = ws;                          // 1,638,400 f
    float*    period_part = ws + 1638400;                // 1,638,400 f
    _Float16* feat_t      = (_Float16*)(ws + 3276800);   // 16*6400*96 f16 = 4,915,200 f
    _Float16* apack_proj  = (_Float16*)(ws + 8192000);   // 16384 f16
    _Float16* apack_fuse  = (_Float16*)(ws + 8200192);   // 55296 f16
    float*    bias1       = ws + 8227840;                // 64
    float*    bias2       = ws + 8227904;                // 64

    prep_kernel<<<288, 256, 0, stream>>>(proj_w, bn1_g, bn1_b, bn1_m, bn1_v,
                                         fuse1_w, bn2_g, bn2_b, bn2_m, bn2_v,
                                         apack_proj, apack_fuse, bias1, bias2);
    edge_period_kernel<<<dim3(16, 16), 512, 0, stream>>>(x, edge_part, period_part);
    density_kernel<<<16, 512, 0, stream>>>(edge_part, period_part, feat_t);
    proj_kernel<<<dim3(100, 16), 256, 0, stream>>>(x, apack_proj, bias1, feat_t);
    fuse_kernel<<<dim3(100, 16), 256, 0, stream>>>(feat_t, apack_fuse,
                                                   bias2, fuse2_w, x, out);
}

// Round 10
// 295.061 us; speedup vs baseline: 4.9411x; 1.8852x over previous
//
#include <hip/hip_runtime.h>
#include <hip/hip_bf16.h>
#include <math.h>

#define HWN 6400
#define CC 256
#define MIDN 64

typedef _Float16 f16x8 __attribute__((ext_vector_type(8)));
typedef _Float16 f16x4 __attribute__((ext_vector_type(4)));
typedef _Float16 h2    __attribute__((ext_vector_type(2)));
typedef float    f32x4 __attribute__((ext_vector_type(4)));
typedef int      i32x4 __attribute__((ext_vector_type(4)));

__device__ __forceinline__ h2 pk2(float a, float b) {
    return __builtin_bit_cast(h2, __builtin_amdgcn_cvt_pkrtz(a, b));
}
__device__ __forceinline__ float h2lo(h2 v) { return (float)v[0]; }
__device__ __forceinline__ float h2hi(h2 v) { return (float)v[1]; }
__device__ __forceinline__ unsigned h2u(h2 v) { return __builtin_bit_cast(unsigned, v); }
__device__ __forceinline__ h2 u2h(unsigned u) { return __builtin_bit_cast(h2, u); }
__device__ __forceinline__ float vsqrtf_(float x) { float r; asm("v_sqrt_f32 %0, %1" : "=v"(r) : "v"(x)); return r; }

// ---------------- K0: fold BN, pack MFMA A-fragments (fp16) ----------------
__global__ void prep_kernel(const float* __restrict__ proj_w,
                            const float* __restrict__ g1, const float* __restrict__ b1,
                            const float* __restrict__ m1, const float* __restrict__ v1,
                            const float* __restrict__ f1w,
                            const float* __restrict__ g2, const float* __restrict__ b2,
                            const float* __restrict__ m2, const float* __restrict__ v2,
                            _Float16* __restrict__ apack_proj,
                            _Float16* __restrict__ apack_fuse,
                            float* __restrict__ bias1, float* __restrict__ bias2) {
    int gid = blockIdx.x * blockDim.x + threadIdx.x;
    int stride = gridDim.x * blockDim.x;
    if (gid < MIDN) {
        float s1 = g1[gid] * rsqrtf(v1[gid] + 1e-5f);
        bias1[gid] = b1[gid] - m1[gid] * s1;
        float s2 = g2[gid] * rsqrtf(v2[gid] + 1e-5f);
        bias2[gid] = b2[gid] - m2[gid] * s2;
    }
    for (int i = gid; i < 8 * 4 * 64 * 8; i += stride) {
        int j = i & 7, lane = (i >> 3) & 63, w = (i >> 9) & 3, c = i >> 11;
        int m = w * 16 + (lane & 15);
        int ch = c * 32 + (lane >> 4) * 8 + j;
        float s1 = g1[m] * rsqrtf(v1[m] + 1e-5f);
        apack_proj[i] = (_Float16)(proj_w[m * CC + ch] * s1);
    }
    for (int i = gid; i < 9 * 3 * 4 * 64 * 8; i += stride) {
        int j = i & 7, lane = (i >> 3) & 63, w = (i >> 9) & 3;
        int tc = i >> 11; int c = tc % 3, t = tc / 3;
        int m = w * 16 + (lane & 15);
        int ch = c * 32 + (lane >> 4) * 8 + j;
        float s2 = g2[m] * rsqrtf(v2[m] + 1e-5f);
        float v = 0.f;
        if (ch < 66) v = f1w[(m * 66 + ch) * 9 + t] * s2;
        apack_fuse[i] = (_Float16)v;
    }
}

// ---------------- K1: edge + period, wave-band column-march ----------------
// grid (32 cg, 16 b), 512 thr = 8 waves; wave w owns rows [10w,10w+10), lane l
// owns cols {l, 64+l(l<16)}. No __syncthreads; wb accesses are volatile +
// sched_barrier-fenced (same-wave cross-lane LDS dependency is invisible to
// LLVM's single-thread alias analysis -> must pin instruction order).
__launch_bounds__(512, 4)
__global__ void edge_period_kernel(const float* __restrict__ x,
                                   unsigned* __restrict__ part) {
    __shared__ unsigned wb[8][88];
    volatile unsigned (*wbv)[88] = wb;
    int tid = threadIdx.x;
    int w = tid >> 6, l = tid & 63;
    int b = blockIdx.y, cg = blockIdx.x;
    int row0 = w * 10;
    int im1 = (l + 63) & 63, ip1 = (l + 1) & 63;
    bool is0 = (l == 0), is63 = (l == 63), isB = (l < 16);

    if (l < 4) wbv[w][(l < 2) ? l : 80 + l] = 0u;   // zero pad cols idx 0,1,82,83
    __builtin_amdgcn_sched_barrier(0);

    // column resize weights (0.5 of Haar folded in)
    float cwA = (l <= 0) ? 1.f : ((l >= 79) ? 0.f : (0.99375f - 0.0125f * (float)l));
    int cB = 64 + l;
    float cwB = (cB >= 79) ? 0.f : (0.99375f - 0.0125f * (float)cB);
    h2 v_pk = pk2(0.5f * cwA, 0.5f * cwB);
    h2 u_pk = pk2(0.5f * (1.f - cwA), 0.5f * (1.f - cwB));

    float erA[10], erB[10], prA[10], prB[10];
#pragma unroll
    for (int k = 0; k < 10; k++) { erA[k] = 0.f; erB[k] = 0.f; prA[k] = 0.f; prB[k] = 0.f; }

#pragma unroll 1
    for (int ch = 0; ch < 8; ch++) {
        const float* xch = x + ((size_t)(b * CC + cg * 8 + ch)) * HWN;
        auto ldtrip = [&](int rr, h2& t0, h2& t1, h2& t2) {
            float a = 0.f, bb = 0.f;
            if (rr >= 0 && rr < 80) {
                a = xch[rr * 80 + l];
                if (isB) bb = xch[rr * 80 + 64 + l];
            }
            h2 xc = pk2(a, bb);
            int xi = __builtin_bit_cast(int, xc);
            unsigned um = (unsigned)__shfl(xi, im1);
            unsigned up = (unsigned)__shfl(xi, ip1);
            um = is0 ? ((um & 0xFFFFu) << 16) : um;   // lane0: {0, col63}
            up = is63 ? (up >> 16) : up;              // lane63: {col64, 0}
            t0 = u2h(um); t1 = xc; t2 = u2h(up);
        };
        h2 xm1_0, xm1_1, xm1_2, x0_0, x0_1, x0_2, xp1_0, xp1_1, xp1_2;
        ldtrip(row0 - 3, xm1_0, xm1_1, xm1_2);
        ldtrip(row0 - 2, x0_0, x0_1, x0_2);
        // seam init: lhc_p/hlc_p = column-resized haar at row pair (row0-3, row0-2)
        h2 lhc_p, hlc_p;
        {
            h2 sa = xm1_0 + x0_0, sb = xm1_1 + x0_1, sc2 = xm1_2 + x0_2;
            h2 da = xm1_0 - x0_0, db = xm1_1 - x0_1, dc = xm1_2 - x0_2;
            lhc_p = u_pk * (sa - sb) + v_pk * (sb - sc2);
            hlc_p = u_pk * (da + db) + v_pk * (db + dc);
        }
        h2 ringA[5], ringB[5];
        float ringSA[5], ringSB[5];
#pragma unroll
        for (int s = 0; s < 14; s++) {
            int r = row0 - 2 + s;
            ldtrip(r + 1, xp1_0, xp1_1, xp1_2);
            // Sobel (own rows only; r in [row0,row0+10) guaranteed for s in [2,12))
            if (s >= 2 && s < 12) {
                h2 gx = (xm1_2 - xm1_0) + (x0_2 - x0_0) + (x0_2 - x0_0) + (xp1_2 - xp1_0);
                h2 gy = (xp1_0 - xm1_0) + (xp1_1 - xm1_1) + (xp1_1 - xm1_1) + (xp1_2 - xm1_2);
                h2 g2v = gx * gx + gy * gy;
                erA[s - 2] += vsqrtf_(h2lo(g2v)) * 0.125f;
                erB[s - 2] += vsqrtf_(h2hi(g2v)) * 0.125f;
            }
            // Haar row pair (r, r+1) -> column-resized lh/hl, then row-resize
            h2 sa = x0_0 + xp1_0, sb = x0_1 + xp1_1, sc2 = x0_2 + xp1_2;
            h2 da = x0_0 - xp1_0, db = x0_1 - xp1_1, dc = x0_2 - xp1_2;
            h2 lhc = u_pk * (sa - sb) + v_pk * (sb - sc2);
            h2 hlc = u_pk * (da + db) + v_pk * (db + dc);
            float cw = (r <= 0) ? 1.f : ((r >= 79) ? 0.f : (0.99375f - 0.0125f * (float)r));
            h2 cwp = pk2(cw, cw), pwp = pk2(1.f - cw, 1.f - cw);
            h2 lhr = pwp * lhc_p + cwp * lhc;
            h2 hlr = pwp * hlc_p + cwp * hlc;
            lhc_p = lhc; hlc_p = hlc;
            unsigned lu = h2u(lhr), hu = h2u(hlr);
            unsigned fA = (lu & 0xFFFFu) | (hu << 16);           // {lh,hl} col l
            unsigned fB = (lu >> 16) | (hu & 0xFFFF0000u);       // {lh,hl} col 64+l
            bool fv = (r >= 0) && (r < 80);
            if (!fv) { fA = 0u; fB = 0u; }
            // horizontal 5-sum via per-wave LDS row; volatile + sched fences
            // pin write->read order (same-wave DS pipe executes in order)
            wbv[w][2 + l] = fA;
            if (isB) wbv[w][66 + l] = fB;
            __builtin_amdgcn_sched_barrier(0);
            unsigned am2 = wbv[w][l], am1 = wbv[w][l + 1], ap1 = wbv[w][l + 3], ap2 = wbv[w][l + 4];
            unsigned bm2 = 0, bm1 = 0, bp1 = 0, bp2 = 0;
            if (isB) { bm2 = wbv[w][64 + l]; bm1 = wbv[w][65 + l]; bp1 = wbv[w][67 + l]; bp2 = wbv[w][68 + l]; }
            __builtin_amdgcn_sched_barrier(0);
            h2 fAh = u2h(fA), fBh = u2h(fB);
            h2 n0 = u2h(am2), n1 = u2h(am1), n2 = u2h(ap1), n3 = u2h(ap2);
            h2 hA = fAh + n0 + n1 + n2 + n3;
            h2 qa = fAh * fAh + n0 * n0 + n1 * n1 + n2 * n2 + n3 * n3;
            float s2A = h2lo(qa) + h2hi(qa);
            h2 m0 = u2h(bm2), m1 = u2h(bm1), m2 = u2h(bp1), m3 = u2h(bp2);
            h2 hB = fBh + m0 + m1 + m2 + m3;
            h2 qb = fBh * fBh + m0 * m0 + m1 * m1 + m2 * m2 + m3 * m3;
            float s2B = h2lo(qb) + h2hi(qb);
            ringA[s % 5] = hA; ringB[s % 5] = hB;
            ringSA[s % 5] = s2A; ringSB[s % 5] = s2B;
            // vertical 5-sum + variance + period emit at row i = r-2
            if (s >= 4) {
                h2 SA = ringA[0] + ringA[1] + ringA[2] + ringA[3] + ringA[4];
                h2 SB = ringB[0] + ringB[1] + ringB[2] + ringB[3] + ringB[4];
                float S2A = ringSA[0] + ringSA[1] + ringSA[2] + ringSA[3] + ringSA[4];
                float S2B = ringSB[0] + ringSB[1] + ringSB[2] + ringSB[3] + ringSB[4];
                float SLA = h2lo(SA), SHA = h2hi(SA);
                float SLB = h2lo(SB), SHB = h2hi(SB);
                float vA = 0.04f * S2A - 0.0016f * (SLA * SLA + SHA * SHA);
                float vB = 0.04f * S2B - 0.0016f * (SLB * SLB + SHB * SHB);
                vA = fmaxf(vA, 0.f) + 1e-6f;
                vB = fmaxf(vB, 0.f) + 1e-6f;
                prA[s - 4] += vsqrtf_(vA);
                prB[s - 4] += vsqrtf_(vB);
            }
            xm1_0 = x0_0; xm1_1 = x0_1; xm1_2 = x0_2;
            x0_0 = xp1_0; x0_1 = xp1_1; x0_2 = xp1_2;
        }
    }
    size_t base = ((size_t)(cg * 16 + b) * 80 + row0) * 80;
#pragma unroll
    for (int k = 0; k < 10; k++) {
        part[base + k * 80 + l] = h2u(pk2(erA[k], prA[k]));
        if (isB) part[base + k * 80 + 64 + l] = h2u(pk2(erB[k], prB[k]));
    }
}

// ---------------- K2: reduce 32 partials + edge density -> feat_t ch 64..95 ----------------
// grid (8 bands, 16 b), 256 threads
__launch_bounds__(256)
__global__ void density_kernel(const unsigned* __restrict__ part,
                               _Float16* __restrict__ feat_t) {
    __shared__ float E[14][84];
    __shared__ float Hs[14][84];
    __shared__ float Ps[10][80];
    int band = blockIdx.x, b = blockIdx.y, tid = threadIdx.x;
    int r0 = band * 10;
    if (tid < 56) { int rr = tid >> 2, c4 = tid & 3; E[rr][(c4 < 2) ? c4 : 80 + c4] = 0.f; }
    for (int idx = tid; idx < 14 * 80; idx += 256) {
        int rr = idx / 80, j = idx - rr * 80;
        int row = r0 - 2 + rr;
        float e = 0.f, p = 0.f;
        if (row >= 0 && row < 80) {
            size_t off = ((size_t)b * 80 + row) * 80 + j;
#pragma unroll 4
            for (int g = 0; g < 32; g++) {
                h2 v = u2h(part[(size_t)g * (16 * 80 * 80) + off]);
                e += h2lo(v); p += h2hi(v);
            }
        }
        E[rr][2 + j] = e * (1.f / 256.f);
        if (rr >= 2 && rr < 12) Ps[rr - 2][j] = p * (1.f / 256.f);
    }
    __syncthreads();
    for (int idx = tid; idx < 14 * 80; idx += 256) {
        int rr = idx / 80, j = idx - rr * 80;
        Hs[rr][2 + j] = E[rr][j] + E[rr][j + 1] + E[rr][j + 2] + E[rr][j + 3] + E[rr][j + 4];
    }
    __syncthreads();
    for (int idx = tid; idx < 10 * 80; idx += 256) {
        int k = idx / 80, j = idx - k * 80;
        int rr = k + 2;
        float pool = Hs[rr - 2][2 + j] + Hs[rr - 1][2 + j] + Hs[rr][2 + j]
                   + Hs[rr + 1][2 + j] + Hs[rr + 2][2 + j];
        float ed = E[rr][2 + j] / (pool * 0.04f + 1e-6f);
        _Float16* fp = feat_t + ((size_t)(b * HWN) + (r0 + k) * 80 + j) * 96;
        f16x8 z8 = {};
        f16x8 f8 = {};
        f8[0] = (_Float16)ed; f8[1] = (_Float16)Ps[k][j];
        *reinterpret_cast<f16x8*>(fp + 64) = f8;
        *reinterpret_cast<f16x8*>(fp + 72) = z8;
        *reinterpret_cast<f16x8*>(fp + 80) = z8;
        *reinterpret_cast<f16x8*>(fp + 88) = z8;
    }
}

// ---------------- K3: proj via MFMA (unchanged) ----------------
__launch_bounds__(256)
__global__ void proj_kernel(const float* __restrict__ x,
                            const _Float16* __restrict__ apack,
                            const float* __restrict__ bias1,
                            _Float16* __restrict__ feat_t) {
    __shared__ __align__(16) unsigned char lds[64 * 512];
    int b = blockIdx.y, p0 = blockIdx.x * 64;
    int tid = threadIdx.x, w = tid >> 6, l = tid & 63;

#pragma unroll 4
    for (int i = 0; i < 16; i++) {
        int ch0 = i * 16 + w * 4;
        f16x4 v4;
#pragma unroll
        for (int q = 0; q < 4; q++)
            v4[q] = (_Float16)x[((size_t)(b * CC + ch0 + q)) * HWN + p0 + l];
        int byte = l * 512 + ((ch0 * 2) ^ ((l & 7) << 4));
        *reinterpret_cast<f16x4*>(lds + byte) = v4;
    }
    __syncthreads();

    const f16x8* Ap = reinterpret_cast<const f16x8*>(apack);
    f32x4 acc[4];
#pragma unroll
    for (int ct = 0; ct < 4; ct++) acc[ct] = (f32x4){0.f, 0.f, 0.f, 0.f};

    int kb = 16 * (l >> 4);
#pragma unroll 2
    for (int c = 0; c < 8; c++) {
        f16x8 a = Ap[(c * 4 + w) * 64 + l];
#pragma unroll
        for (int ct = 0; ct < 4; ct++) {
            int byte = (ct * 16 + (l & 15)) * 512 + ((c * 64 + kb) ^ ((l & 7) << 4));
            f16x8 bv = *reinterpret_cast<const f16x8*>(lds + byte);
            acc[ct] = __builtin_amdgcn_mfma_f32_16x16x32_f16(a, bv, acc[ct], 0, 0, 0);
        }
    }

    float b1v[4];
#pragma unroll
    for (int q = 0; q < 4; q++) b1v[q] = bias1[w * 16 + (l >> 4) * 4 + q];
#pragma unroll
    for (int ct = 0; ct < 4; ct++) {
        f16x4 o4;
#pragma unroll
        for (int q = 0; q < 4; q++) {
            float z = acc[ct][q] + b1v[q];
            o4[q] = (_Float16)(z / (1.f + expf(-z)));
        }
        size_t px = (size_t)(b * HWN) + p0 + ct * 16 + (l & 15);
        *reinterpret_cast<f16x4*>(feat_t + px * 96 + w * 16 + (l >> 4) * 4) = o4;
    }
}

// ---------------- K4: fuse via MFMA + epilogue + x*wgt (unchanged) ----------------
#define TROW 256
__launch_bounds__(256)
__global__ void fuse_kernel(const _Float16* __restrict__ feat_t,
                            const _Float16* __restrict__ apack,
                            const float* __restrict__ bias2,
                            const float* __restrict__ fuse2,
                            const float* __restrict__ x,
                            float* __restrict__ out) {
    __shared__ __align__(16) unsigned char tl[108 * TROW];
    __shared__ float R[4 * 4 * 4 * 16];
    __shared__ float wgtbuf[64];
    int b = blockIdx.y, t5 = blockIdx.x;
    int ti = t5 / 5, tj = t5 - ti * 5;
    int i0 = ti * 4, j0 = tj * 16;
    int tid = threadIdx.x, w = tid >> 6, l = tid & 63;

    for (int idx = tid; idx < 1296; idx += 256) {
        int hpx = idx / 12, g = idx - hpx * 12;
        int hr = hpx / 18, hc = hpx - hr * 18;
        int gi = i0 - 1 + hr, gj = j0 - 1 + hc;
        i32x4 val = {0, 0, 0, 0};
        if (gi >= 0 && gi < 80 && gj >= 0 && gj < 80) {
            val = *reinterpret_cast<const i32x4*>(
                feat_t + ((size_t)(b * HWN) + gi * 80 + gj) * 96 + g * 8);
        }
        *reinterpret_cast<i32x4*>(tl + hpx * TROW + ((g * 16) ^ ((hc & 7) << 4))) = val;
    }
    __syncthreads();

    const f16x8* Ap = reinterpret_cast<const f16x8*>(apack);
    f32x4 acc[4];
#pragma unroll
    for (int r = 0; r < 4; r++) acc[r] = (f32x4){0.f, 0.f, 0.f, 0.f};
    int kb = 16 * (l >> 4);

#pragma unroll 1
    for (int t = 0; t < 9; t++) {
        int dy = t / 3, dx = t - dy * 3;
        f16x8 a0 = Ap[((t * 3 + 0) * 4 + w) * 64 + l];
        f16x8 a1 = Ap[((t * 3 + 1) * 4 + w) * 64 + l];
        f16x8 a2 = Ap[((t * 3 + 2) * 4 + w) * 64 + l];
        int hc = (l & 15) + dx;
        int key = (hc & 7) << 4;
#pragma unroll
        for (int r = 0; r < 4; r++) {
            int base = ((r + dy) * 18 + hc) * TROW;
            f16x8 b0 = *reinterpret_cast<const f16x8*>(tl + base + ((0 + kb) ^ key));
            acc[r] = __builtin_amdgcn_mfma_f32_16x16x32_f16(a0, b0, acc[r], 0, 0, 0);
            f16x8 b1_ = *reinterpret_cast<const f16x8*>(tl + base + ((64 + kb) ^ key));
            acc[r] = __builtin_amdgcn_mfma_f32_16x16x32_f16(a1, b1_, acc[r], 0, 0, 0);
            f16x8 b2_ = *reinterpret_cast<const f16x8*>(tl + base + ((128 + kb) ^ key));
            acc[r] = __builtin_amdgcn_mfma_f32_16x16x32_f16(a2, b2_, acc[r], 0, 0, 0);
        }
    }

    float b2v[4], f2v[4];
#pragma unroll
    for (int q = 0; q < 4; q++) {
        int m = w * 16 + (l >> 4) * 4 + q;
        b2v[q] = bias2[m];
        f2v[q] = fuse2[m];
    }
#pragma unroll
    for (int r = 0; r < 4; r++) {
        float p = 0.f;
#pragma unroll
        for (int q = 0; q < 4; q++) {
            float z = acc[r][q] + b2v[q];
            p += f2v[q] * (z / (1.f + expf(-z)));
        }
        R[((w * 4 + r) * 4 + (l >> 4)) * 16 + (l & 15)] = p;
    }
    __syncthreads();
    if (tid < 64) {
        int r = tid >> 4, cc = tid & 15;
        float s = 0.f;
#pragma unroll
        for (int w2 = 0; w2 < 4; w2++)
#pragma unroll
            for (int g2 = 0; g2 < 4; g2++)
                s += R[((w2 * 4 + r) * 4 + g2) * 16 + cc];
        wgtbuf[tid] = 1.f / (1.f + expf(-s));
    }
    __syncthreads();

    int r = l >> 4, cc = l & 15;
    float wgt = wgtbuf[l];
    size_t base = (size_t)b * CC * HWN + (size_t)((i0 + r) * 80 + j0 + cc);
    const float* xp = x + base;
    float* op = out + base;
#pragma unroll 4
    for (int ch = w * 64; ch < w * 64 + 64; ch++) {
        op[(size_t)ch * HWN] = xp[(size_t)ch * HWN] * wgt;
    }
}

// ---------------- launch ----------------
extern "C" void kernel_launch(void* const* d_in, const int* in_sizes, int n_in,
                              void* d_out, int out_size, void* d_ws, size_t ws_size,
                              hipStream_t stream) {
    (void)in_sizes; (void)n_in; (void)out_size; (void)ws_size;
    const float* x       = (const float*)d_in[0];
    const float* proj_w  = (const float*)d_in[1];
    const float* bn1_g   = (const float*)d_in[2];
    const float* bn1_b   = (const float*)d_in[3];
    const float* bn1_m   = (const float*)d_in[4];
    const float* bn1_v   = (const float*)d_in[5];
    const float* fuse1_w = (const float*)d_in[6];
    const float* bn2_g   = (const float*)d_in[7];
    const float* bn2_b   = (const float*)d_in[8];
    const float* bn2_m   = (const float*)d_in[9];
    const float* bn2_v   = (const float*)d_in[10];
    const float* fuse2_w = (const float*)d_in[11];
    float* out = (float*)d_out;

    float* ws = (float*)d_ws;
    unsigned* part        = (unsigned*)ws;               // 32*16*80*80 = 3,276,800 uints
    _Float16* feat_t      = (_Float16*)(ws + 3276800);   // 16*6400*96 f16 = 4,915,200 f
    _Float16* apack_proj  = (_Float16*)(ws + 8192000);   // 16384 f16 = 8,192 f
    _Float16* apack_fuse  = (_Float16*)(ws + 8200192);   // 55296 f16 = 27,648 f
    float*    bias1       = ws + 8227840;
    float*    bias2       = ws + 8227904;

    prep_kernel<<<288, 256, 0, stream>>>(proj_w, bn1_g, bn1_b, bn1_m, bn1_v,
                                         fuse1_w, bn2_g, bn2_b, bn2_m, bn2_v,
                                         apack_proj, apack_fuse, bias1, bias2);
    edge_period_kernel<<<dim3(32, 16), 512, 0, stream>>>(x, part);
    density_kernel<<<dim3(8, 16), 256, 0, stream>>>(part, feat_t);
    proj_kernel<<<dim3(100, 16), 256, 0, stream>>>(x, apack_proj, bias1, feat_t);
    fuse_kernel<<<dim3(100, 16), 256, 0, stream>>>(feat_t, apack_fuse,
                                                   bias2, fuse2_w, x, out);
}